// Round 6
// baseline (248.848 us; speedup 1.0000x reference)
//
#include <hip/hip_runtime.h>
#include <math.h>

// LIF recurrence: v = v + (x_t - v)/tau; s = sigmoid(v - th); v *= (1 - s)
// x: [B=32, T=512, D=2048] fp32 -> spikes s, same shape.
//
// R6: sequential-stream blocks. Evidence: R2/R4b/R5 all saturate at
// ~2.5-3.1 TB/s regardless of occupancy (2-8 waves/SIMD), load width
// (256B-1KB/instr) or pipelining, with EXACT traffic (R5: FETCH=WRITE=
// 131MB) — while fillBuffer hits 6.6 TB/s in the same capture. The only
// invariant across the slow configs: each thread walks t at 8KB stride,
// so DRAM sees loosely-synchronized 1-4KB fragments per row instead of
// long sequential runs -> service-rate cap ~ half of achievable.
// Fix: block = (b, segment) covering ALL of D. Per row, the block's 4
// waves issue 8 x 1KB fully-contiguous loads = the whole 8KB row; rows
// advance sequentially -> each block is one contiguous 256KB read stream
// + one 128KB write stream (copy-kernel pattern, 2048 streams chip-wide).
// Each thread owns 8 chains: d in [4t,4t+4) and [1024+4t,1024+4t+4).
//
// Parallel-in-time math IDENTICAL to R5 (S=32, SEG=16, W=16, validated
// absmax 0.00390625): contraction |dv_t/dv_{t-1}| <= ~0.52, cold-start
// error after 16 warmup steps ~1e-4 in v -> ~4e-5 in s, invisible.
// sg==0 runs a dummy warmup on its own rows then resets v=0 (uniform).
//
// Pipeline: double-buffered 4-row chunks; next chunk's loads are issued
// BEFORE this chunk's stores, so the vmcnt wait for loads never drains
// stores (stores were issued after the loads being waited on).
// VGPR: buf 2x4x2xf32x4=64 + state/addr ~ 30 -> fits 128 (launch_bounds
// (256,4)); grid 1024 blocks = 4 blocks/CU = 16 waves/CU.

#define TAU_INV 0.5f
#define TH 1.0f

typedef __attribute__((ext_vector_type(4))) float f32x4;

constexpr int BATCH = 32;
constexpr int TT = 512;
constexpr int DD = 2048;
constexpr int S = 32;            // segments per chain
constexpr int SEG = TT / S;      // 16 stored rows per block
constexpr int W = 16;            // warmup rows
constexpr int U = 4;             // rows per chunk
constexpr int NC_W = W / U;      // 4 warmup chunks
constexpr int NC_M = SEG / U;    // 4 stored chunks
constexpr int NC = NC_W + NC_M;  // 8 chunks

__global__ __launch_bounds__(256, 4) void lif_kernel(const float* __restrict__ x,
                                                     float* __restrict__ out) {
    const int bid = blockIdx.x;
    const int sg = bid & (S - 1);      // uniform per block
    const int b = bid >> 5;
    const int tid = threadIdx.x;       // 0..255
    const int t0 = sg * SEG;
    const bool warm = (sg != 0);

    // Two 1KB-contiguous wave-loads per row cover the full 8KB row.
    const size_t offA = (size_t)4 * tid;            // d: [4t, 4t+4)
    const size_t offB = (size_t)(DD / 2) + 4 * tid; // d: [1024+4t, ...)

    // Warmup rows [t0-W, t0) for sg>0 (contiguous with main -> one
    // unbroken 32-row stream); sg==0 dummy-reads its own [t0, t0+W).
    const float* xw = x + ((size_t)b * TT + (warm ? t0 - W : t0)) * DD;
    const float* xm = x + ((size_t)b * TT + t0) * DD;
    float* om = out + ((size_t)b * TT + t0) * DD;

    f32x4 buf[2][U][2];

    auto load_chunk = [&](int slot, int c) {
        const float* base = (c < NC_W)
                                ? xw + (size_t)c * U * DD
                                : xm + (size_t)(c - NC_W) * U * DD;
        #pragma unroll
        for (int r = 0; r < U; ++r) {
            buf[slot][r][0] =
                *reinterpret_cast<const f32x4*>(base + (size_t)r * DD + offA);
            buf[slot][r][1] =
                *reinterpret_cast<const f32x4*>(base + (size_t)r * DD + offB);
        }
    };

    load_chunk(0, 0);

    f32x4 va = {0.f, 0.f, 0.f, 0.f};
    f32x4 vb = {0.f, 0.f, 0.f, 0.f};

    #pragma unroll
    for (int c = 0; c < NC; ++c) {
        const int cur = c & 1;

        // Prefetch chunk c+1 BEFORE chunk c's stores (see header note).
        if (c + 1 < NC) load_chunk(cur ^ 1, c + 1);

        #pragma unroll
        for (int r = 0; r < U; ++r) {
            f32x4 sa, sb;
            #pragma unroll
            for (int e = 0; e < 4; ++e) {
                // chain A[e]
                va[e] = va[e] + (buf[cur][r][0][e] - va[e]) * TAU_INV;
                sa[e] = __builtin_amdgcn_rcpf(1.0f + __expf(TH - va[e]));
                va[e] = va[e] * (1.0f - sa[e]);
                // chain B[e]
                vb[e] = vb[e] + (buf[cur][r][1][e] - vb[e]) * TAU_INV;
                sb[e] = __builtin_amdgcn_rcpf(1.0f + __expf(TH - vb[e]));
                vb[e] = vb[e] * (1.0f - sb[e]);
            }
            if (c >= NC_W) {
                float* o = om + (size_t)((c - NC_W) * U + r) * DD;
                __builtin_nontemporal_store(sa, reinterpret_cast<f32x4*>(o + offA));
                __builtin_nontemporal_store(sb, reinterpret_cast<f32x4*>(o + offB));
            }
        }

        // sg==0's warmup was a dummy — restore true initial state.
        if (c == NC_W - 1 && !warm) {
            va = (f32x4){0.f, 0.f, 0.f, 0.f};
            vb = (f32x4){0.f, 0.f, 0.f, 0.f};
        }
    }
}

extern "C" void kernel_launch(void* const* d_in, const int* in_sizes, int n_in,
                              void* d_out, int out_size, void* d_ws, size_t ws_size,
                              hipStream_t stream) {
    const float* x = (const float*)d_in[0];
    float* out = (float*)d_out;
    const int threads = 256;
    const int blocks = BATCH * S;                        // 1024 blocks
    lif_kernel<<<blocks, threads, 0, stream>>>(x, out);
}